// Round 2
// baseline (926.175 us; speedup 1.0000x reference)
//
#include <hip/hip_runtime.h>

// LocalConsistencyLoss: N=500000 points, C=20 classes, K=16 neighbors.
// out = mean over valid points of (masked mean over neighbors of ||p_i - p_j||^2)

static constexpr int kC = 20;          // classes (20 floats = 5 float4, 80B row)
static constexpr int kK = 16;          // neighbors per point
static constexpr float kLossWeight = 1.0f;

// ---------- Kernel 1: row softmax, float4-vectorized (rows are 16B-aligned: 80B each)
__global__ void softmax_rows(const float* __restrict__ logits,
                             float* __restrict__ probs, int n) {
    int i = blockIdx.x * blockDim.x + threadIdx.x;
    if (i >= n) return;
    const float4* in4  = reinterpret_cast<const float4*>(logits) + (size_t)i * 5;
    float4*       out4 = reinterpret_cast<float4*>(probs)        + (size_t)i * 5;
    float4 r[5];
    float mx = -3.0e38f;
#pragma unroll
    for (int c = 0; c < 5; ++c) {
        r[c] = in4[c];
        mx = fmaxf(mx, fmaxf(fmaxf(r[c].x, r[c].y), fmaxf(r[c].z, r[c].w)));
    }
    float sum = 0.f;
#pragma unroll
    for (int c = 0; c < 5; ++c) {
        r[c].x = __expf(r[c].x - mx); sum += r[c].x;
        r[c].y = __expf(r[c].y - mx); sum += r[c].y;
        r[c].z = __expf(r[c].z - mx); sum += r[c].z;
        r[c].w = __expf(r[c].w - mx); sum += r[c].w;
    }
    float inv = 1.0f / sum;
#pragma unroll
    for (int c = 0; c < 5; ++c) {
        r[c].x *= inv; r[c].y *= inv; r[c].z *= inv; r[c].w *= inv;
        out4[c] = r[c];
    }
}

// ---------- device helper: load row + softmax into registers (fallback path)
__device__ __forceinline__ void load_softmax_row(const float4* __restrict__ row4,
                                                 float4 (&r)[5]) {
    float mx = -3.0e38f;
#pragma unroll
    for (int c = 0; c < 5; ++c) {
        r[c] = row4[c];
        mx = fmaxf(mx, fmaxf(fmaxf(r[c].x, r[c].y), fmaxf(r[c].z, r[c].w)));
    }
    float sum = 0.f;
#pragma unroll
    for (int c = 0; c < 5; ++c) {
        r[c].x = __expf(r[c].x - mx); sum += r[c].x;
        r[c].y = __expf(r[c].y - mx); sum += r[c].y;
        r[c].z = __expf(r[c].z - mx); sum += r[c].z;
        r[c].w = __expf(r[c].w - mx); sum += r[c].w;
    }
    float inv = 1.0f / sum;
#pragma unroll
    for (int c = 0; c < 5; ++c) { r[c].x *= inv; r[c].y *= inv; r[c].z *= inv; r[c].w *= inv; }
}

// ---------- shared epilogue: group-16 reduce -> per-point mean -> block reduce -> atomics
__device__ __forceinline__ void reduce_and_accumulate(float dist, float maskf,
                                                      bool leader_valid, int k,
                                                      float* __restrict__ accum) {
    float sd = dist * maskf;
    float nv = maskf;
#pragma unroll
    for (int off = 8; off >= 1; off >>= 1) {
        sd += __shfl_down(sd, off, 16);
        nv += __shfl_down(nv, off, 16);
    }
    float num = 0.f, den = 0.f;
    if (k == 0 && leader_valid) {
        num = sd / fmaxf(nv, 1.0f);
        den = 1.0f;
    }
#pragma unroll
    for (int off = 32; off >= 1; off >>= 1) {
        num += __shfl_xor(num, off);
        den += __shfl_xor(den, off);
    }
    __shared__ float s_num[4], s_den[4];
    int wave = threadIdx.x >> 6;
    if ((threadIdx.x & 63) == 0) { s_num[wave] = num; s_den[wave] = den; }
    __syncthreads();
    if (threadIdx.x == 0) {
        atomicAdd(&accum[0], s_num[0] + s_num[1] + s_num[2] + s_num[3]);
        atomicAdd(&accum[1], s_den[0] + s_den[1] + s_den[2] + s_den[3]);
    }
}

// ---------- Kernel 2: one thread per (point, neighbor) pair; probs precomputed
__global__ void dist_kernel(const float* __restrict__ probs,
                            const int* __restrict__ nbr,
                            const int* __restrict__ labels,
                            float* __restrict__ accum, int n) {
    int t = blockIdx.x * blockDim.x + threadIdx.x;
    int pt = t >> 4;
    int k  = t & 15;
    bool in_range = (pt < n);
    int ptc = in_range ? pt : (n - 1);

    int lab = labels[ptc];
    bool valid = in_range && (lab != -1);

    int nb = in_range ? nbr[t] : -1;
    float maskf = (valid && nb >= 0) ? 1.0f : 0.0f;
    int idx = nb; if (idx < 0) idx = 0; if (idx > n - 1) idx = n - 1;

    const float4* p4 = reinterpret_cast<const float4*>(probs);
    const float4* a4 = p4 + (size_t)ptc * 5;
    const float4* b4 = p4 + (size_t)idx * 5;
    float dist = 0.f;
#pragma unroll
    for (int c = 0; c < 5; ++c) {
        float4 a = a4[c];
        float4 b = b4[c];
        float dx = a.x - b.x, dy = a.y - b.y, dz = a.z - b.z, dw = a.w - b.w;
        dist += dx * dx + dy * dy + dz * dz + dw * dw;
    }
    reduce_and_accumulate(dist, maskf, valid, k, accum);
}

// ---------- Fallback: fused (no probs scratch); recomputes softmax inline
__global__ void fused_dist_kernel(const float* __restrict__ logits,
                                  const int* __restrict__ nbr,
                                  const int* __restrict__ labels,
                                  float* __restrict__ accum, int n) {
    int t = blockIdx.x * blockDim.x + threadIdx.x;
    int pt = t >> 4;
    int k  = t & 15;
    bool in_range = (pt < n);
    int ptc = in_range ? pt : (n - 1);

    int lab = labels[ptc];
    bool valid = in_range && (lab != -1);

    int nb = in_range ? nbr[t] : -1;
    float maskf = (valid && nb >= 0) ? 1.0f : 0.0f;
    int idx = nb; if (idx < 0) idx = 0; if (idx > n - 1) idx = n - 1;

    const float4* l4 = reinterpret_cast<const float4*>(logits);
    float4 a[5], b[5];
    load_softmax_row(l4 + (size_t)ptc * 5, a);
    load_softmax_row(l4 + (size_t)idx * 5, b);
    float dist = 0.f;
#pragma unroll
    for (int c = 0; c < 5; ++c) {
        float dx = a[c].x - b[c].x, dy = a[c].y - b[c].y;
        float dz = a[c].z - b[c].z, dw = a[c].w - b[c].w;
        dist += dx * dx + dy * dy + dz * dz + dw * dw;
    }
    reduce_and_accumulate(dist, maskf, valid, k, accum);
}

// ---------- finalize
__global__ void finalize_kernel(const float* __restrict__ accum, float* __restrict__ out) {
    out[0] = accum[0] / fmaxf(accum[1], 1.0f) * kLossWeight;
}

extern "C" void kernel_launch(void* const* d_in, const int* in_sizes, int n_in,
                              void* d_out, int out_size, void* d_ws, size_t ws_size,
                              hipStream_t stream) {
    const float* logits = (const float*)d_in[0];   // [N, 20] f32
    const int*   nbr    = (const int*)d_in[1];     // [N, 16] int
    const int*   labels = (const int*)d_in[2];     // [N] int
    float* out = (float*)d_out;

    int n = in_sizes[0] / kC;                      // N = 500000
    float* accum = (float*)d_ws;                   // 2 floats at offset 0
    hipMemsetAsync(d_ws, 0, 16, stream);

    const size_t probs_off = 16;                   // keep float4 alignment
    const size_t need = probs_off + (size_t)n * kC * sizeof(float);

    long long pairs = (long long)n * kK;           // 8,000,000
    int blocks2 = (int)((pairs + 255) / 256);

    if (ws_size >= need) {
        float* probs = (float*)((char*)d_ws + probs_off);
        int blocks1 = (n + 255) / 256;
        softmax_rows<<<blocks1, 256, 0, stream>>>(logits, probs, n);
        dist_kernel<<<blocks2, 256, 0, stream>>>(probs, nbr, labels, accum, n);
    } else {
        fused_dist_kernel<<<blocks2, 256, 0, stream>>>(logits, nbr, labels, accum, n);
    }
    finalize_kernel<<<1, 1, 0, stream>>>(accum, out);
}

// Round 5
// 506.004 us; speedup vs baseline: 1.8304x; 1.8304x over previous
//
#include <hip/hip_runtime.h>
#include <hip/hip_fp16.h>

// LocalConsistencyLoss: N=500000, C=20, K=16.
// out = mean over valid points of (masked mean over neighbors of ||p_i - p_j||^2)
//
// Strategy: softmax -> fp16-packed probs (40B rows, 20MB). Gathers are made
// L2-resident by slicing the neighbor-index space into 8 ranges (2.5MB fp16
// each < 4MB per-XCD L2) and running one pass per slice; same-stream launches
// serialize passes so every CU gathers from the same resident slice.
// Per-point partials accumulate non-atomically (one 16-lane group owns a point).

static constexpr int kC = 20;          // classes (fp16 row = 40 B = 5 x 8B words)
static constexpr int kK = 16;          // neighbors per point
static constexpr int kSlices = 8;
static constexpr float kLossWeight = 1.0f;

union H2U { __half2 h; unsigned int u; };

// ---------- Kernel 1: row softmax (fp32 math), pack to fp16
__global__ void softmax_pack(const float* __restrict__ logits,
                             __half* __restrict__ probs, int n) {
    int i = blockIdx.x * blockDim.x + threadIdx.x;
    if (i >= n) return;
    const float4* in4 = reinterpret_cast<const float4*>(logits) + (size_t)i * 5;
    float4 r[5];
    float mx = -3.0e38f;
#pragma unroll
    for (int c = 0; c < 5; ++c) {
        r[c] = in4[c];
        mx = fmaxf(mx, fmaxf(fmaxf(r[c].x, r[c].y), fmaxf(r[c].z, r[c].w)));
    }
    float sum = 0.f;
#pragma unroll
    for (int c = 0; c < 5; ++c) {
        r[c].x = __expf(r[c].x - mx); sum += r[c].x;
        r[c].y = __expf(r[c].y - mx); sum += r[c].y;
        r[c].z = __expf(r[c].z - mx); sum += r[c].z;
        r[c].w = __expf(r[c].w - mx); sum += r[c].w;
    }
    float inv = 1.0f / sum;
    unsigned long long* out8 =
        reinterpret_cast<unsigned long long*>(probs + (size_t)i * kC); // 40B rows, 8B-aligned
#pragma unroll
    for (int c = 0; c < 5; ++c) {
        H2U lo, hi;
        lo.h = __floats2half2_rn(r[c].x * inv, r[c].y * inv);
        hi.h = __floats2half2_rn(r[c].z * inv, r[c].w * inv);
        out8[c] = (unsigned long long)lo.u | ((unsigned long long)hi.u << 32);
    }
}

// ---------- Kernel 2 (x8): gather pass restricted to neighbor rows in [lo,hi)
__global__ void slice_pass(const __half* __restrict__ probs,
                           const int* __restrict__ nbr,
                           float* __restrict__ sd, float* __restrict__ nv,
                           int n, int lo, int hi) {
    int t = blockIdx.x * blockDim.x + threadIdx.x;
    int pt = t >> 4;
    if (pt >= n) return;
    int k = t & 15;
    int nb = __builtin_nontemporal_load(nbr + t);      // coalesced stream
    bool act = (nb >= lo) && (nb < hi);                 // nb==-1 excluded (lo>=0)
    unsigned long long ball = __ballot(act);
    unsigned gm = (unsigned)((ball >> (threadIdx.x & 48)) & 0xFFFFull);
    if (gm == 0u) return;                               // whole 16-group idle this pass

    float dist = 0.f, m = 0.f;
    if (act) {
        const unsigned long long* a8 =
            reinterpret_cast<const unsigned long long*>(probs + (size_t)pt * kC);
        const unsigned long long* b8 =
            reinterpret_cast<const unsigned long long*>(probs + (size_t)nb * kC);
        float d2 = 0.f;
#pragma unroll
        for (int c = 0; c < 5; ++c) {
            unsigned long long av = __builtin_nontemporal_load(a8 + c); // own row: stream
            unsigned long long bv = b8[c];                              // slice row: cache it
            H2U ax, ay, bx, by;
            ax.u = (unsigned int)av; ay.u = (unsigned int)(av >> 32);
            bx.u = (unsigned int)bv; by.u = (unsigned int)(bv >> 32);
            float2 a0 = __half22float2(ax.h), a1 = __half22float2(ay.h);
            float2 b0 = __half22float2(bx.h), b1 = __half22float2(by.h);
            float dx = a0.x - b0.x, dy = a0.y - b0.y;
            float dz = a1.x - b1.x, dw = a1.y - b1.y;
            d2 += dx * dx + dy * dy + dz * dz + dw * dw;
        }
        dist = d2; m = 1.f;
    }
#pragma unroll
    for (int off = 8; off >= 1; off >>= 1) {
        dist += __shfl_down(dist, off, 16);
        m    += __shfl_down(m, off, 16);
    }
    if (k == 0) {            // non-atomic RMW: this group is the only writer of pt,
        sd[pt] += dist;      // and passes are serialized on the stream
        nv[pt] += m;
    }
}

// ---------- Kernel 3: per-point mean + masked global reduction
__global__ void final_reduce(const float* __restrict__ sd, const float* __restrict__ nv,
                             const int* __restrict__ labels,
                             float* __restrict__ accum, int n) {
    int i = blockIdx.x * blockDim.x + threadIdx.x;
    float num = 0.f, den = 0.f;
    if (i < n) {
        int lab = labels[i];
        if (lab != -1) {
            num = sd[i] / fmaxf(nv[i], 1.0f);
            den = 1.0f;
        }
    }
#pragma unroll
    for (int off = 32; off >= 1; off >>= 1) {
        num += __shfl_xor(num, off);
        den += __shfl_xor(den, off);
    }
    __shared__ float s_num[4], s_den[4];
    int wave = threadIdx.x >> 6;
    if ((threadIdx.x & 63) == 0) { s_num[wave] = num; s_den[wave] = den; }
    __syncthreads();
    if (threadIdx.x == 0) {
        atomicAdd(&accum[0], s_num[0] + s_num[1] + s_num[2] + s_num[3]);
        atomicAdd(&accum[1], s_den[0] + s_den[1] + s_den[2] + s_den[3]);
    }
}

// ---------- Fallback (small ws): fp32 fused, one thread per pair
__device__ __forceinline__ void load_softmax_row_f32(const float4* __restrict__ row4,
                                                     float4 (&r)[5]) {
    float mx = -3.0e38f;
#pragma unroll
    for (int c = 0; c < 5; ++c) {
        r[c] = row4[c];
        mx = fmaxf(mx, fmaxf(fmaxf(r[c].x, r[c].y), fmaxf(r[c].z, r[c].w)));
    }
    float sum = 0.f;
#pragma unroll
    for (int c = 0; c < 5; ++c) {
        r[c].x = __expf(r[c].x - mx); sum += r[c].x;
        r[c].y = __expf(r[c].y - mx); sum += r[c].y;
        r[c].z = __expf(r[c].z - mx); sum += r[c].z;
        r[c].w = __expf(r[c].w - mx); sum += r[c].w;
    }
    float inv = 1.0f / sum;
#pragma unroll
    for (int c = 0; c < 5; ++c) { r[c].x *= inv; r[c].y *= inv; r[c].z *= inv; r[c].w *= inv; }
}

__global__ void fused_dist_kernel(const float* __restrict__ logits,
                                  const int* __restrict__ nbr,
                                  const int* __restrict__ labels,
                                  float* __restrict__ accum, int n) {
    int t = blockIdx.x * blockDim.x + threadIdx.x;
    int pt = t >> 4;
    int k  = t & 15;
    bool in_range = (pt < n);
    int ptc = in_range ? pt : (n - 1);
    int lab = labels[ptc];
    bool valid = in_range && (lab != -1);
    int nb = in_range ? nbr[t] : -1;
    float maskf = (valid && nb >= 0) ? 1.0f : 0.0f;
    int idx = nb; if (idx < 0) idx = 0; if (idx > n - 1) idx = n - 1;

    const float4* l4 = reinterpret_cast<const float4*>(logits);
    float4 a[5], b[5];
    load_softmax_row_f32(l4 + (size_t)ptc * 5, a);
    load_softmax_row_f32(l4 + (size_t)idx * 5, b);
    float dist = 0.f;
#pragma unroll
    for (int c = 0; c < 5; ++c) {
        float dx = a[c].x - b[c].x, dy = a[c].y - b[c].y;
        float dz = a[c].z - b[c].z, dw = a[c].w - b[c].w;
        dist += dx * dx + dy * dy + dz * dz + dw * dw;
    }
    float sdv = dist * maskf, nvv = maskf;
#pragma unroll
    for (int off = 8; off >= 1; off >>= 1) {
        sdv += __shfl_down(sdv, off, 16);
        nvv += __shfl_down(nvv, off, 16);
    }
    float num = 0.f, den = 0.f;
    if (k == 0 && valid) { num = sdv / fmaxf(nvv, 1.0f); den = 1.0f; }
#pragma unroll
    for (int off = 32; off >= 1; off >>= 1) {
        num += __shfl_xor(num, off);
        den += __shfl_xor(den, off);
    }
    __shared__ float s_num[4], s_den[4];
    int wave = threadIdx.x >> 6;
    if ((threadIdx.x & 63) == 0) { s_num[wave] = num; s_den[wave] = den; }
    __syncthreads();
    if (threadIdx.x == 0) {
        atomicAdd(&accum[0], s_num[0] + s_num[1] + s_num[2] + s_num[3]);
        atomicAdd(&accum[1], s_den[0] + s_den[1] + s_den[2] + s_den[3]);
    }
}

// ---------- finalize
__global__ void finalize_kernel(const float* __restrict__ accum, float* __restrict__ out) {
    out[0] = accum[0] / fmaxf(accum[1], 1.0f) * kLossWeight;
}

extern "C" void kernel_launch(void* const* d_in, const int* in_sizes, int n_in,
                              void* d_out, int out_size, void* d_ws, size_t ws_size,
                              hipStream_t stream) {
    const float* logits = (const float*)d_in[0];   // [N, 20] f32
    const int*   nbr    = (const int*)d_in[1];     // [N, 16] int32
    const int*   labels = (const int*)d_in[2];     // [N] int32
    float* out = (float*)d_out;

    int n = in_sizes[0] / kC;                      // N = 500000
    long long pairs = (long long)n * kK;           // 8,000,000
    int blocks_pairs = (int)((pairs + 255) / 256);
    int blocks_pts   = (n + 255) / 256;

    // workspace layout: [accum 2f pad64][sd Nf][nv Nf][probs fp16 N*20]
    float* accum = (float*)d_ws;
    size_t sd_off = 64;
    size_t nv_off = 64 + (size_t)n * 4;
    size_t probs_off = ((64 + (size_t)n * 8) + 15) & ~(size_t)15;
    size_t need = probs_off + (size_t)n * kC * sizeof(__half);

    if (ws_size >= need) {
        float*  sd    = (float*)((char*)d_ws + sd_off);
        float*  nv    = (float*)((char*)d_ws + nv_off);
        __half* probs = (__half*)((char*)d_ws + probs_off);

        (void)hipMemsetAsync(d_ws, 0, 64 + (size_t)n * 8, stream); // accum + sd + nv

        softmax_pack<<<blocks_pts, 256, 0, stream>>>(logits, probs, n);

        int slice = (n + kSlices - 1) / kSlices;   // 62500
        for (int s = 0; s < kSlices; ++s) {
            int lo = s * slice;
            int hi = lo + slice; if (hi > n) hi = n;
            slice_pass<<<blocks_pairs, 256, 0, stream>>>(probs, nbr, sd, nv, n, lo, hi);
        }
        final_reduce<<<blocks_pts, 256, 0, stream>>>(sd, nv, labels, accum, n);
    } else {
        (void)hipMemsetAsync(d_ws, 0, 16, stream);
        fused_dist_kernel<<<blocks_pairs, 256, 0, stream>>>(logits, nbr, labels, accum, n);
    }
    finalize_kernel<<<1, 1, 0, stream>>>(accum, out);
}

// Round 6
// 504.602 us; speedup vs baseline: 1.8355x; 1.0028x over previous
//
#include <hip/hip_runtime.h>
#include <hip/hip_fp16.h>
#include <hip/hip_cooperative_groups.h>

namespace cg = cooperative_groups;

// LocalConsistencyLoss: N=500000, C=20, K=16.
// out = mean over valid points of (masked mean over neighbors of ||p_i - p_j||^2)
//
// Coop persistent kernel: one thread per point holds its 16 neighbor indices,
// its own fp16 prob row, and its sd/nv accumulators in REGISTERS across all 8
// slice phases (grid.sync between phases keeps every XCD gathering from the
// same L2-resident 2.5MB slice). Eliminates the 8x index re-read, 8x own-row
// re-read, and sd/nv global RMW of the multi-kernel version.

static constexpr int kC = 20;          // classes (fp16 row = 40 B = 5 x 8B words)
static constexpr int kK = 16;          // neighbors per point
static constexpr int kSlices = 8;
static constexpr float kLossWeight = 1.0f;

union H2U { __half2 h; unsigned int u; };

__device__ __forceinline__ float4 unpack4(unsigned long long w) {
    H2U a, b; a.u = (unsigned int)w; b.u = (unsigned int)(w >> 32);
    float2 lo = __half22float2(a.h), hi = __half22float2(b.h);
    return make_float4(lo.x, lo.y, hi.x, hi.y);
}

// ---------- Kernel 1: row softmax (fp32 math), pack to fp16
__global__ void softmax_pack(const float* __restrict__ logits,
                             __half* __restrict__ probs, int n) {
    int i = blockIdx.x * blockDim.x + threadIdx.x;
    if (i >= n) return;
    const float4* in4 = reinterpret_cast<const float4*>(logits) + (size_t)i * 5;
    float4 r[5];
    float mx = -3.0e38f;
#pragma unroll
    for (int c = 0; c < 5; ++c) {
        r[c] = in4[c];
        mx = fmaxf(mx, fmaxf(fmaxf(r[c].x, r[c].y), fmaxf(r[c].z, r[c].w)));
    }
    float sum = 0.f;
#pragma unroll
    for (int c = 0; c < 5; ++c) {
        r[c].x = __expf(r[c].x - mx); sum += r[c].x;
        r[c].y = __expf(r[c].y - mx); sum += r[c].y;
        r[c].z = __expf(r[c].z - mx); sum += r[c].z;
        r[c].w = __expf(r[c].w - mx); sum += r[c].w;
    }
    float inv = 1.0f / sum;
    unsigned long long* out8 =
        reinterpret_cast<unsigned long long*>(probs + (size_t)i * kC); // 40B rows, 8B-aligned
#pragma unroll
    for (int c = 0; c < 5; ++c) {
        H2U lo, hi;
        lo.h = __floats2half2_rn(r[c].x * inv, r[c].y * inv);
        hi.h = __floats2half2_rn(r[c].z * inv, r[c].w * inv);
        out8[c] = (unsigned long long)lo.u | ((unsigned long long)hi.u << 32);
    }
}

// ---------- Cooperative persistent kernel: all slices + final reduction
__global__ __launch_bounds__(256, 8)
void persistent_pass(const __half* __restrict__ probs,
                     const int* __restrict__ nbr,
                     const int* __restrict__ labels,
                     float* __restrict__ accum,
                     float* __restrict__ out,
                     int n, int slice) {
    cg::grid_group grid = cg::this_grid();
    int pt = blockIdx.x * blockDim.x + threadIdx.x;
    bool live = (pt < n);

    int nbs[kK];                       // 16 VGPRs: neighbor indices, persistent
    unsigned long long own[5];         // 10 VGPRs: own fp16 row, persistent
    if (live) {
        const unsigned long long* idx8 =
            reinterpret_cast<const unsigned long long*>(nbr + (size_t)pt * kK); // 64B row
#pragma unroll
        for (int q = 0; q < 8; ++q) {
            unsigned long long w = __builtin_nontemporal_load(idx8 + q);
            nbs[2 * q]     = (int)(unsigned int)(w & 0xFFFFFFFFull);
            nbs[2 * q + 1] = (int)(unsigned int)(w >> 32);
        }
        const unsigned long long* a8 =
            reinterpret_cast<const unsigned long long*>(probs + (size_t)pt * kC);
#pragma unroll
        for (int c = 0; c < 5; ++c) own[c] = __builtin_nontemporal_load(a8 + c);
    } else {
#pragma unroll
        for (int q = 0; q < kK; ++q) nbs[q] = -1;
#pragma unroll
        for (int c = 0; c < 5; ++c) own[c] = 0ull;
    }

    float sd = 0.f, nv = 0.f;
    int lo = 0;
    for (int s = 0; s < kSlices; ++s) {
        int hi = lo + slice; if (hi > n) hi = n;
        if (live) {
#pragma unroll
            for (int k = 0; k < kK; ++k) {
                int nb = nbs[k];
                if (nb >= lo && nb < hi) {            // nb==-1 never active
                    const unsigned long long* b8 =
                        reinterpret_cast<const unsigned long long*>(probs + (size_t)nb * kC);
                    float d2 = 0.f;
#pragma unroll
                    for (int c = 0; c < 5; ++c) {
                        float4 a = unpack4(own[c]);
                        float4 b = unpack4(b8[c]);    // slice row: cacheable, L2-resident
                        float dx = a.x - b.x, dy = a.y - b.y;
                        float dz = a.z - b.z, dw = a.w - b.w;
                        d2 += dx * dx + dy * dy + dz * dz + dw * dw;
                    }
                    sd += d2; nv += 1.f;
                }
            }
        }
        lo = hi;
        grid.sync();                                   // keep all XCDs on the same slice
    }

    // per-point mean + label mask + block reduce + global atomic
    float num = 0.f, den = 0.f;
    if (live) {
        int lab = labels[pt];
        if (lab != -1) { num = sd / fmaxf(nv, 1.0f); den = 1.0f; }
    }
#pragma unroll
    for (int off = 32; off >= 1; off >>= 1) {
        num += __shfl_xor(num, off);
        den += __shfl_xor(den, off);
    }
    __shared__ float s_num[4], s_den[4];
    int wave = threadIdx.x >> 6;
    if ((threadIdx.x & 63) == 0) { s_num[wave] = num; s_den[wave] = den; }
    __syncthreads();
    if (threadIdx.x == 0) {
        atomicAdd(&accum[0], s_num[0] + s_num[1] + s_num[2] + s_num[3]);
        atomicAdd(&accum[1], s_den[0] + s_den[1] + s_den[2] + s_den[3]);
    }

    grid.sync();                                       // atomics visible device-wide
    if (pt == 0) out[0] = accum[0] / fmaxf(accum[1], 1.0f) * kLossWeight;
}

// ================= Fallback path (round-5 proven kernels) =================

__global__ void slice_pass(const __half* __restrict__ probs,
                           const int* __restrict__ nbr,
                           float* __restrict__ sd, float* __restrict__ nv,
                           int n, int lo, int hi) {
    int t = blockIdx.x * blockDim.x + threadIdx.x;
    int pt = t >> 4;
    if (pt >= n) return;
    int k = t & 15;
    int nb = __builtin_nontemporal_load(nbr + t);
    bool act = (nb >= lo) && (nb < hi);
    unsigned long long ball = __ballot(act);
    unsigned gm = (unsigned)((ball >> (threadIdx.x & 48)) & 0xFFFFull);
    if (gm == 0u) return;

    float dist = 0.f, m = 0.f;
    if (act) {
        const unsigned long long* a8 =
            reinterpret_cast<const unsigned long long*>(probs + (size_t)pt * kC);
        const unsigned long long* b8 =
            reinterpret_cast<const unsigned long long*>(probs + (size_t)nb * kC);
        float d2 = 0.f;
#pragma unroll
        for (int c = 0; c < 5; ++c) {
            unsigned long long av = __builtin_nontemporal_load(a8 + c);
            unsigned long long bv = b8[c];
            float4 a = unpack4(av);
            float4 b = unpack4(bv);
            float dx = a.x - b.x, dy = a.y - b.y;
            float dz = a.z - b.z, dw = a.w - b.w;
            d2 += dx * dx + dy * dy + dz * dz + dw * dw;
        }
        dist = d2; m = 1.f;
    }
#pragma unroll
    for (int off = 8; off >= 1; off >>= 1) {
        dist += __shfl_down(dist, off, 16);
        m    += __shfl_down(m, off, 16);
    }
    if (k == 0) { sd[pt] += dist; nv[pt] += m; }
}

__global__ void final_reduce(const float* __restrict__ sd, const float* __restrict__ nv,
                             const int* __restrict__ labels,
                             float* __restrict__ accum, int n) {
    int i = blockIdx.x * blockDim.x + threadIdx.x;
    float num = 0.f, den = 0.f;
    if (i < n) {
        int lab = labels[i];
        if (lab != -1) { num = sd[i] / fmaxf(nv[i], 1.0f); den = 1.0f; }
    }
#pragma unroll
    for (int off = 32; off >= 1; off >>= 1) {
        num += __shfl_xor(num, off);
        den += __shfl_xor(den, off);
    }
    __shared__ float s_num[4], s_den[4];
    int wave = threadIdx.x >> 6;
    if ((threadIdx.x & 63) == 0) { s_num[wave] = num; s_den[wave] = den; }
    __syncthreads();
    if (threadIdx.x == 0) {
        atomicAdd(&accum[0], s_num[0] + s_num[1] + s_num[2] + s_num[3]);
        atomicAdd(&accum[1], s_den[0] + s_den[1] + s_den[2] + s_den[3]);
    }
}

__global__ void finalize_kernel(const float* __restrict__ accum, float* __restrict__ out) {
    out[0] = accum[0] / fmaxf(accum[1], 1.0f) * kLossWeight;
}

extern "C" void kernel_launch(void* const* d_in, const int* in_sizes, int n_in,
                              void* d_out, int out_size, void* d_ws, size_t ws_size,
                              hipStream_t stream) {
    const float* logits = (const float*)d_in[0];   // [N, 20] f32
    const int*   nbr    = (const int*)d_in[1];     // [N, 16] int32
    const int*   labels = (const int*)d_in[2];     // [N] int32
    float* out = (float*)d_out;

    int n = in_sizes[0] / kC;                      // N = 500000
    long long pairs = (long long)n * kK;
    int blocks_pairs = (int)((pairs + 255) / 256);
    int blocks_pts   = (n + 255) / 256;            // 1954

    // workspace layout: [accum 2f pad64][sd Nf][nv Nf][probs fp16 N*20]
    float* accum = (float*)d_ws;
    size_t sd_off = 64;
    size_t nv_off = 64 + (size_t)n * 4;
    size_t probs_off = ((64 + (size_t)n * 8) + 15) & ~(size_t)15;
    size_t need = probs_off + (size_t)n * kC * sizeof(__half);

    if (ws_size >= need) {
        float*  sd    = (float*)((char*)d_ws + sd_off);
        float*  nv    = (float*)((char*)d_ws + nv_off);
        __half* probs = (__half*)((char*)d_ws + probs_off);

        (void)hipMemsetAsync(d_ws, 0, 64 + (size_t)n * 8, stream); // accum + sd + nv

        softmax_pack<<<blocks_pts, 256, 0, stream>>>(logits, probs, n);

        int slice = (n + kSlices - 1) / kSlices;   // 62500

        // ---- gate: can all blocks_pts blocks be co-resident? ----
        bool coop_ok = false;
        {
            int dev = 0, cus = 256, perCU = 0;
            (void)hipGetDevice(&dev);
            if (hipDeviceGetAttribute(&cus, hipDeviceAttributeMultiprocessorCount, dev)
                != hipSuccess) cus = 256;
            if (hipOccupancyMaxActiveBlocksPerMultiprocessor(
                    &perCU, persistent_pass, 256, 0) == hipSuccess) {
                coop_ok = ((long long)perCU * cus >= (long long)blocks_pts);
            }
        }
        if (coop_ok) {
            const __half* probs_c = probs;
            void* args[] = { (void*)&probs_c, (void*)&nbr, (void*)&labels,
                             (void*)&accum, (void*)&out, (void*)&n, (void*)&slice };
            hipError_t e = hipLaunchCooperativeKernel(
                (const void*)persistent_pass, dim3(blocks_pts), dim3(256),
                args, 0, stream);
            if (e != hipSuccess) { (void)hipGetLastError(); coop_ok = false; }
        }
        if (!coop_ok) {
            for (int s = 0; s < kSlices; ++s) {
                int lo = s * slice;
                int hi = lo + slice; if (hi > n) hi = n;
                slice_pass<<<blocks_pairs, 256, 0, stream>>>(probs, nbr, sd, nv, n, lo, hi);
            }
            final_reduce<<<blocks_pts, 256, 0, stream>>>(sd, nv, labels, accum, n);
            finalize_kernel<<<1, 1, 0, stream>>>(accum, out);
        }
    } else {
        // ws too small for probs: nothing to stage; just run the simple fused path
        // (slow but correct): recompute softmax per pair in fp32.
        (void)hipMemsetAsync(d_ws, 0, 16, stream);
        // reuse slice machinery impossible without probs; fall back to a single
        // fused kernel over all pairs.
        // (kept minimal: this path is not expected to trigger with 24MB+ ws)
        // fused kernel:
        struct Local {};
        // launch fused
        extern __global__ void fused_dist_kernel(const float*, const int*, const int*, float*, int);
        fused_dist_kernel<<<blocks_pairs, 256, 0, stream>>>(logits, nbr, labels, accum, n);
        finalize_kernel<<<1, 1, 0, stream>>>(accum, out);
    }
}

// fp32 fused ultra-fallback (ws too small) — one thread per pair
__device__ __forceinline__ void load_softmax_row_f32(const float4* __restrict__ row4,
                                                     float4 (&r)[5]) {
    float mx = -3.0e38f;
#pragma unroll
    for (int c = 0; c < 5; ++c) {
        r[c] = row4[c];
        mx = fmaxf(mx, fmaxf(fmaxf(r[c].x, r[c].y), fmaxf(r[c].z, r[c].w)));
    }
    float sum = 0.f;
#pragma unroll
    for (int c = 0; c < 5; ++c) {
        r[c].x = __expf(r[c].x - mx); sum += r[c].x;
        r[c].y = __expf(r[c].y - mx); sum += r[c].y;
        r[c].z = __expf(r[c].z - mx); sum += r[c].z;
        r[c].w = __expf(r[c].w - mx); sum += r[c].w;
    }
    float inv = 1.0f / sum;
#pragma unroll
    for (int c = 0; c < 5; ++c) { r[c].x *= inv; r[c].y *= inv; r[c].z *= inv; r[c].w *= inv; }
}

__global__ void fused_dist_kernel(const float* __restrict__ logits,
                                  const int* __restrict__ nbr,
                                  const int* __restrict__ labels,
                                  float* __restrict__ accum, int n) {
    int t = blockIdx.x * blockDim.x + threadIdx.x;
    int pt = t >> 4;
    int k  = t & 15;
    bool in_range = (pt < n);
    int ptc = in_range ? pt : (n - 1);
    int lab = labels[ptc];
    bool valid = in_range && (lab != -1);
    int nb = in_range ? nbr[t] : -1;
    float maskf = (valid && nb >= 0) ? 1.0f : 0.0f;
    int idx = nb; if (idx < 0) idx = 0; if (idx > n - 1) idx = n - 1;

    const float4* l4 = reinterpret_cast<const float4*>(logits);
    float4 a[5], b[5];
    load_softmax_row_f32(l4 + (size_t)ptc * 5, a);
    load_softmax_row_f32(l4 + (size_t)idx * 5, b);
    float dist = 0.f;
#pragma unroll
    for (int c = 0; c < 5; ++c) {
        float dx = a[c].x - b[c].x, dy = a[c].y - b[c].y;
        float dz = a[c].z - b[c].z, dw = a[c].w - b[c].w;
        dist += dx * dx + dy * dy + dz * dz + dw * dw;
    }
    float sdv = dist * maskf, nvv = maskf;
#pragma unroll
    for (int off = 8; off >= 1; off >>= 1) {
        sdv += __shfl_down(sdv, off, 16);
        nvv += __shfl_down(nvv, off, 16);
    }
    float num = 0.f, den = 0.f;
    if (k == 0 && valid) { num = sdv / fmaxf(nvv, 1.0f); den = 1.0f; }
#pragma unroll
    for (int off = 32; off >= 1; off >>= 1) {
        num += __shfl_xor(num, off);
        den += __shfl_xor(den, off);
    }
    __shared__ float s_num[4], s_den[4];
    int wave = threadIdx.x >> 6;
    if ((threadIdx.x & 63) == 0) { s_num[wave] = num; s_den[wave] = den; }
    __syncthreads();
    if (threadIdx.x == 0) {
        atomicAdd(&accum[0], s_num[0] + s_num[1] + s_num[2] + s_num[3]);
        atomicAdd(&accum[1], s_den[0] + s_den[1] + s_den[2] + s_den[3]);
    }
}